// Round 6
// baseline (56.286 us; speedup 1.0000x reference)
//
#include <hip/hip_runtime.h>
#include <hip/hip_fp16.h>
#include <math.h>
#include <stdint.h>

#define U 50
#define TT 100
#define BB 256

typedef _Float16 half2v __attribute__((ext_vector_type(2)));

// Hard-constrained dot2: forces both operands into arch VGPRs at every use,
// making VGPR-home strictly cheaper than AGPR-home for the weight array.
__device__ __forceinline__ void dot2_asm(float& acc, uint32_t h2, uint32_t w2) {
    asm("v_dot2_f32_f16 %0, %1, %2, %0" : "+v"(acc) : "v"(h2), "v"(w2));
}

__device__ __forceinline__ float sigmoid_fast(float x) {
    return 1.0f / (1.0f + __expf(-x));
}
__device__ __forceinline__ float tanh_fast(float x) {
    float e = __expf(2.0f * x);
    return 1.0f - 2.0f / (e + 1.0f);
}
__device__ __forceinline__ float param_act(float x, float mn, float mx) {
    float scale = 0.5f * (mx - mn);
    return tanh_fast(x) * scale + mn + scale;
}

// One wave per batch element. Lane l (<50) owns LSTM unit l; the four gate
// columns of rec are 100 packed-f16 uint32 values consumed by inline-asm
// v_dot2_f32_f16 ("v" constraints -> must be VGPR-resident at every use).
// h is exchanged through LDS; reload vectorized as 6x b128 + 1x b32.
__global__ __launch_bounds__(64, 1) void encoder_kernel(
    const float* __restrict__ x,        // (B,T,4)
    const float* __restrict__ state,    // (B,T,4)
    const float* __restrict__ kernel,   // (4,200)
    const float* __restrict__ rec,      // (50,200)
    const float* __restrict__ bias,     // (200,)
    const float* __restrict__ w_dv, const float* __restrict__ b_dv,
    const float* __restrict__ w_dt, const float* __restrict__ b_dt,
    const float* __restrict__ w_mj, const float* __restrict__ b_mj,
    const float* __restrict__ w_ma, const float* __restrict__ b_ma,
    const float* __restrict__ w_mi, const float* __restrict__ b_mi,
    float* __restrict__ out)            // act_seq (B*T) then idm (B*5)
{
    const int b = blockIdx.x;
    const int l = threadIdx.x;
    const int cl = (l < U) ? l : (U - 1);   // clamped column (no per-weight cndmask)

    __shared__ __align__(16) _Float16 h16[64];  // 50 used; dword k = packed pair k
    __shared__ float idm[8];

    // rcpu[g*25+j] = packed( rec[2j][g*50+cl], rec[2j+1][g*50+cl] )
    uint32_t rcpu[100];
    #pragma unroll
    for (int g = 0; g < 4; ++g) {
        #pragma unroll
        for (int j = 0; j < 25; ++j) {
            float a  = rec[(2 * j) * 200 + g * U + cl];
            float c2 = rec[(2 * j + 1) * 200 + g * U + cl];
            half2v p; p.x = (_Float16)a; p.y = (_Float16)c2;
            rcpu[g * 25 + j] = __builtin_bit_cast(uint32_t, p);
        }
    }
    #pragma unroll
    for (int j = 0; j < 100; ++j) asm volatile("" : "+v"(rcpu[j]));

    float kc[16];
    #pragma unroll
    for (int g = 0; g < 4; ++g)
        #pragma unroll
        for (int f = 0; f < 4; ++f)
            kc[g * 4 + f] = kernel[f * 200 + g * U + cl];

    float bz[4];
    #pragma unroll
    for (int g = 0; g < 4; ++g) bz[g] = bias[g * U + cl];

    h16[l] = (_Float16)0.0f;
    float c = 0.0f;

    const float4* __restrict__ xb4 = (const float4*)(x + (size_t)b * TT * 4);
    const uint4* __restrict__ hq = (const uint4*)h16;       // 6 x b128
    const uint32_t* __restrict__ hd = (const uint32_t*)h16; // + 1 x b32 (dword 24)

    float4 x4 = xb4[0];

    // software-pipelined h fragment (zeros for t=0): hvu[k] = packed pair k
    uint32_t hvu[25];
    {
        #pragma unroll
        for (int q = 0; q < 6; ++q) {
            uint4 v = hq[q];
            hvu[4 * q + 0] = v.x; hvu[4 * q + 1] = v.y;
            hvu[4 * q + 2] = v.z; hvu[4 * q + 3] = v.w;
        }
        hvu[24] = hd[24];
    }

    for (int t = 0; t < TT; ++t) {
        float4 x4n = xb4[(t + 1 < TT) ? (t + 1) : t];  // prefetch

        // x-part (independent of h)
        float zx[4];
        #pragma unroll
        for (int g = 0; g < 4; ++g) {
            zx[g] = fmaf(x4.x, kc[g * 4 + 0],
                    fmaf(x4.y, kc[g * 4 + 1],
                    fmaf(x4.z, kc[g * 4 + 2],
                    fmaf(x4.w, kc[g * 4 + 3], bz[g]))));
        }

        // 100 v_dot2_f32_f16, 8 interleaved accumulator chains
        float acc[8] = {0.f, 0.f, 0.f, 0.f, 0.f, 0.f, 0.f, 0.f};
        #pragma unroll
        for (int j = 0; j < 25; ++j) {
            const int s = (j & 1) * 4;
            dot2_asm(acc[s + 0], hvu[j], rcpu[0 * 25 + j]);
            dot2_asm(acc[s + 1], hvu[j], rcpu[1 * 25 + j]);
            dot2_asm(acc[s + 2], hvu[j], rcpu[2 * 25 + j]);
            dot2_asm(acc[s + 3], hvu[j], rcpu[3 * 25 + j]);
        }

        float zi = zx[0] + acc[0] + acc[4];
        float zf = zx[1] + acc[1] + acc[5];
        float zg = zx[2] + acc[2] + acc[6];
        float zo = zx[3] + acc[3] + acc[7];

        float ig = sigmoid_fast(zi);
        float fg = sigmoid_fast(zf);
        float gg = tanh_fast(zg);
        float og = sigmoid_fast(zo);
        c = fmaf(fg, c, ig * gg);
        float hnew = og * tanh_fast(c);
        if (l < U) h16[l] = (_Float16)hnew;

        // re-read h immediately (latency overlaps next x-part); 7 vector reads
        #pragma unroll
        for (int q = 0; q < 6; ++q) {
            uint4 v = hq[q];
            hvu[4 * q + 0] = v.x; hvu[4 * q + 1] = v.y;
            hvu[4 * q + 2] = v.z; hvu[4 * q + 3] = v.w;
        }
        hvu[24] = hd[24];

        x4 = x4n;
        // no barrier: single wave, in-order LDS pipeline + compiler lgkmcnt
    }

    // ---- 5 output heads (lanes 0..4) ----
    if (l < 5) {
        const float* w  = (l == 0) ? w_dv : (l == 1) ? w_dt :
                          (l == 2) ? w_mj : (l == 3) ? w_ma : w_mi;
        const float* bb = (l == 0) ? b_dv : (l == 1) ? b_dt :
                          (l == 2) ? b_mj : (l == 3) ? b_ma : b_mi;
        float s = bb[0];
        #pragma unroll
        for (int j = 0; j < U; ++j) s = fmaf((float)h16[j], w[j], s);
        float v;
        if (l == 0)      v = param_act(s, 15.0f, 35.0f);
        else if (l == 1) v = param_act(s, 0.5f, 3.0f);
        else if (l == 2) v = fmaxf(s, 0.0f);
        else if (l == 3) v = param_act(s, 0.5f, 3.0f);
        else             v = param_act(s, 0.5f, 4.0f);
        idm[l] = v;
        out[BB * TT + b * 5 + l] = v;
    }

    // ---- IDM physics over T ----
    const float desired_v    = idm[0];
    const float desired_tgap = idm[1];
    const float min_jamx     = idm[2];
    const float max_act      = idm[3];
    const float min_act      = idm[4];
    const float inv_tsab = 1.0f / (2.0f * sqrtf(max_act * min_act));
    const float inv_dv   = 1.0f / desired_v;

    const float4* __restrict__ sb4 = (const float4*)(state + (size_t)b * TT * 4);
    for (int t = l; t < TT; t += 64) {
        float4 s4 = sb4[t];
        float vel = s4.x;
        float dv  = s4.z;
        float dx  = s4.w;
        float dgap = fmaf(desired_tgap, vel, fmaf(vel * dv, inv_tsab, min_jamx));
        float r1 = vel * inv_dv;
        r1 = r1 * r1;
        r1 = r1 * r1;            // ^4
        float r2 = dgap / dx;
        r2 = r2 * r2;            // ^2
        out[b * TT + t] = max_act * (1.0f - (r1 + r2));
    }
}

extern "C" void kernel_launch(void* const* d_in, const int* in_sizes, int n_in,
                              void* d_out, int out_size, void* d_ws, size_t ws_size,
                              hipStream_t stream) {
    const float* x      = (const float*)d_in[0];
    const float* state  = (const float*)d_in[1];
    const float* kern   = (const float*)d_in[2];
    const float* rec    = (const float*)d_in[3];
    const float* bias   = (const float*)d_in[4];
    const float* w_dv   = (const float*)d_in[5];
    const float* b_dv   = (const float*)d_in[6];
    const float* w_dt   = (const float*)d_in[7];
    const float* b_dt   = (const float*)d_in[8];
    const float* w_mj   = (const float*)d_in[9];
    const float* b_mj   = (const float*)d_in[10];
    const float* w_ma   = (const float*)d_in[11];
    const float* b_ma   = (const float*)d_in[12];
    const float* w_mi   = (const float*)d_in[13];
    const float* b_mi   = (const float*)d_in[14];
    float* out = (float*)d_out;

    encoder_kernel<<<BB, 64, 0, stream>>>(
        x, state, kern, rec, bias,
        w_dv, b_dv, w_dt, b_dt, w_mj, b_mj, w_ma, b_ma, w_mi, b_mi,
        out);
}